// Round 7
// baseline (294.282 us; speedup 1.0000x reference)
//
#include <hip/hip_runtime.h>
#include <hip/hip_bf16.h>

typedef __bf16 bf16x8 __attribute__((ext_vector_type(8)));
typedef float f32x4 __attribute__((ext_vector_type(4)));
typedef unsigned short ushort8 __attribute__((ext_vector_type(8)));

#define B_    4
#define Q_    100
#define QPAD  112
#define D_    128
#define C_    20
#define N_    262144
#define TN    256   // points per block: 4 waves x 4 strips x 16 rows
#define LROW  136   // padded LDS row (ushorts): 272B stride
#define LN_EPS 1e-5f

// ---------------- Kernel 1: LayerNorm + MLP head + class head ----------------
__global__ __launch_bounds__(128) void head_kernel(
    const float* __restrict__ qf,
    const float* __restrict__ gamma, const float* __restrict__ beta,
    const float* __restrict__ W1, const float* __restrict__ b1,
    const float* __restrict__ W2, const float* __restrict__ b2,
    const float* __restrict__ Wc, const float* __restrict__ bc,
    float* __restrict__ out_class,
    unsigned short* __restrict__ me_hi, unsigned short* __restrict__ me_lo)
{
    const int q = blockIdx.x;   // 0..QPAD-1
    const int b = blockIdx.y;   // 0..3
    const int t = threadIdx.x;  // 0..127

    unsigned short* mh = me_hi + (b * QPAD + q) * D_;
    unsigned short* ml = me_lo + (b * QPAD + q) * D_;
    if (q >= Q_) { mh[t] = 0; ml[t] = 0; return; }  // zero pad rows (uniform branch)

    __shared__ float red[D_];
    __shared__ float qs[D_];
    __shared__ float hs[D_];

    const float x = qf[(b * Q_ + q) * D_ + t];

    red[t] = x;
    __syncthreads();
    #pragma unroll
    for (int s = 64; s > 0; s >>= 1) { if (t < s) red[t] += red[t + s]; __syncthreads(); }
    const float mu = red[0] * (1.0f / 128.0f);
    __syncthreads();
    const float xc = x - mu;
    red[t] = xc * xc;
    __syncthreads();
    #pragma unroll
    for (int s = 64; s > 0; s >>= 1) { if (t < s) red[t] += red[t + s]; __syncthreads(); }
    const float var = red[0] * (1.0f / 128.0f);

    const float xn = xc * rsqrtf(var + LN_EPS) * gamma[t] + beta[t];
    qs[t] = xn;
    __syncthreads();

    // h = relu(qn @ W1^T + b1)
    {
        const float4* wr = (const float4*)(W1 + t * D_);
        float p0 = 0.f, p1 = 0.f, p2 = 0.f, p3 = 0.f;
        #pragma unroll
        for (int d4 = 0; d4 < 32; ++d4) {
            const float4 w = wr[d4];
            const int d = d4 * 4;
            p0 = fmaf(w.x, qs[d + 0], p0);
            p1 = fmaf(w.y, qs[d + 1], p1);
            p2 = fmaf(w.z, qs[d + 2], p2);
            p3 = fmaf(w.w, qs[d + 3], p3);
        }
        hs[t] = fmaxf((p0 + p1) + (p2 + p3) + b1[t], 0.0f);
    }
    __syncthreads();

    // mask_embed = h @ W2^T + b2 -> split bf16 hi/lo
    {
        const float4* wr = (const float4*)(W2 + t * D_);
        float p0 = 0.f, p1 = 0.f, p2 = 0.f, p3 = 0.f;
        #pragma unroll
        for (int d4 = 0; d4 < 32; ++d4) {
            const float4 w = wr[d4];
            const int d = d4 * 4;
            p0 = fmaf(w.x, hs[d + 0], p0);
            p1 = fmaf(w.y, hs[d + 1], p1);
            p2 = fmaf(w.z, hs[d + 2], p2);
            p3 = fmaf(w.w, hs[d + 3], p3);
        }
        const float me = (p0 + p1) + (p2 + p3) + b2[t];
        const __bf16 hi = (__bf16)me;
        const __bf16 lo = (__bf16)(me - (float)hi);
        mh[t] = __builtin_bit_cast(unsigned short, hi);
        ml[t] = __builtin_bit_cast(unsigned short, lo);
    }

    // class head
    if (t < C_) {
        const float4* wr = (const float4*)(Wc + t * D_);
        float p0 = 0.f, p1 = 0.f, p2 = 0.f, p3 = 0.f;
        #pragma unroll
        for (int d4 = 0; d4 < 32; ++d4) {
            const float4 w = wr[d4];
            const int d = d4 * 4;
            p0 = fmaf(w.x, qs[d + 0], p0);
            p1 = fmaf(w.y, qs[d + 1], p1);
            p2 = fmaf(w.z, qs[d + 2], p2);
            p3 = fmaf(w.w, qs[d + 3], p3);
        }
        out_class[(b * Q_ + q) * C_ + t] = (p0 + p1) + (p2 + p3) + bc[t];
    }
}

// ---------------- Kernel 2 helpers ----------------
__device__ __forceinline__ void load_strip(const float* __restrict__ prow,
                                           float4 fv[8], int kg)
{
    #pragma unroll
    for (int kt = 0; kt < 4; ++kt) {
        fv[2 * kt]     = *(const float4*)(prow + kt * 32 + kg * 8);
        fv[2 * kt + 1] = *(const float4*)(prow + kt * 32 + kg * 8 + 4);
    }
}

__device__ __forceinline__ void conv_strip(const float4 fv[8],
                                           bf16x8 AH[4], bf16x8 AL[4])
{
    #pragma unroll
    for (int kt = 0; kt < 4; ++kt) {
        const float f0[4] = {fv[2*kt].x, fv[2*kt].y, fv[2*kt].z, fv[2*kt].w};
        const float f1[4] = {fv[2*kt+1].x, fv[2*kt+1].y, fv[2*kt+1].z, fv[2*kt+1].w};
        #pragma unroll
        for (int j = 0; j < 4; ++j) {
            const __bf16 h0 = (__bf16)f0[j];
            AH[kt][j] = h0;
            AL[kt][j] = (__bf16)(f0[j] - (float)h0);
            const __bf16 h1 = (__bf16)f1[j];
            AH[kt][j + 4] = h1;
            AL[kt][j + 4] = (__bf16)(f1[j] - (float)h1);
        }
    }
}

// ---------------- Kernel 2: ragged point_feats @ mask_embed^T via MFMA ----------------
// 256 threads = 4 waves; each wave owns 4 strips (64 points). Per qt the wave
// reads bh/bl from LDS ONCE and runs 4 independent 12-MFMA chains (48 MFMA per
// 8 ds_read_b128 -> LDS demand /4, 4-way MFMA ILP). A-loads are 2-deep
// software-pipelined at block start; steady state is barrier-free.
__global__ __launch_bounds__(256, 2) void mask_kernel(
    const float* __restrict__ points, const int* __restrict__ bids,
    const unsigned short* __restrict__ me_hi, const unsigned short* __restrict__ me_lo,
    float* __restrict__ outm)
{
    const int n0   = blockIdx.x * TN;
    const int tid  = threadIdx.x;
    const int wave = tid >> 6;      // 0..3
    const int lane = tid & 63;
    const int ar   = lane & 15;     // A row within strip
    const int kg   = lane >> 4;     // k-group 0..3
    const int qlane = lane & 15;    // C/D col within q-tile
    const int r0   = n0 + wave * 64;

    __shared__ unsigned short BH[QPAD][LROW];
    __shared__ unsigned short BL[QPAD][LROW];

    // 2-deep A-load pipeline across the wave's 4 strips
    float4 fva[8], fvb[8];
    load_strip(points + (size_t)(r0 + 0 * 16 + ar) * D_, fva, kg);
    load_strip(points + (size_t)(r0 + 1 * 16 + ar) * D_, fvb, kg);

    // packed 2-bit row->batch map for this lane's 16 output rows
    unsigned int pk = 0;
    #pragma unroll
    for (int s = 0; s < 4; ++s) {
        #pragma unroll
        for (int rr = 0; rr < 4; ++rr) {
            pk |= (unsigned)bids[r0 + s * 16 + kg * 4 + rr] << ((s * 4 + rr) * 2);
        }
    }
    const int b_lo = bids[n0];
    const int b_hi = bids[n0 + TN - 1];

    // A frag (16x16x32): lane holds A[lane&15][(lane>>4)*8 + j], j=0..7
    bf16x8 AH[4][4], AL[4][4];
    conv_strip(fva, AH[0], AL[0]);
    load_strip(points + (size_t)(r0 + 2 * 16 + ar) * D_, fva, kg);
    conv_strip(fvb, AH[1], AL[1]);
    load_strip(points + (size_t)(r0 + 3 * 16 + ar) * D_, fvb, kg);
    conv_strip(fva, AH[2], AL[2]);
    conv_strip(fvb, AH[3], AL[3]);

    for (int b = b_lo; b <= b_hi; ++b) {
        if (b != b_lo) __syncthreads();     // prior-b LDS reads done before restage
        // stage mask_embed[b] hi/lo into LDS (7 iters x 256 threads)
        {
            const ushort8* sh = (const ushort8*)(me_hi + (size_t)b * QPAD * D_);
            const ushort8* sl = (const ushort8*)(me_lo + (size_t)b * QPAD * D_);
            for (int c = tid; c < QPAD * D_ / 8; c += 256) {
                const int row = c >> 4;
                const int col = c & 15;
                *(ushort8*)&BH[row][col * 8] = sh[c];
                *(ushort8*)&BL[row][col * 8] = sl[c];
            }
        }
        __syncthreads();

        #pragma unroll
        for (int qt = 0; qt < 7; ++qt) {
            const int qrow = qt * 16 + qlane;
            // B frags once per qt (B frag: lane holds B[(lane>>4)*8+j][lane&15])
            bf16x8 bh[4], bl[4];
            #pragma unroll
            for (int kt = 0; kt < 4; ++kt) {
                const int kb = kt * 32 + kg * 8;
                bh[kt] = __builtin_bit_cast(bf16x8, *(const ushort8*)&BH[qrow][kb]);
                bl[kt] = __builtin_bit_cast(bf16x8, *(const ushort8*)&BL[qrow][kb]);
            }
            // 4 independent accumulator chains (one per strip)
            #pragma unroll
            for (int s = 0; s < 4; ++s) {
                f32x4 acc = {0.f, 0.f, 0.f, 0.f};
                #pragma unroll
                for (int kt = 0; kt < 4; ++kt) {
                    acc = __builtin_amdgcn_mfma_f32_16x16x32_bf16(AL[s][kt], bh[kt], acc, 0, 0, 0);
                    acc = __builtin_amdgcn_mfma_f32_16x16x32_bf16(AH[s][kt], bl[kt], acc, 0, 0, 0);
                    acc = __builtin_amdgcn_mfma_f32_16x16x32_bf16(AH[s][kt], bh[kt], acc, 0, 0, 0);
                }
                if (qrow < Q_) {
                    #pragma unroll
                    for (int rr = 0; rr < 4; ++rr) {
                        if (((pk >> ((s * 4 + rr) * 2)) & 3u) == (unsigned)b) {
                            outm[(size_t)(r0 + s * 16 + kg * 4 + rr) * Q_ + qrow] = acc[rr];
                        }
                    }
                }
            }
        }
    }
}

extern "C" void kernel_launch(void* const* d_in, const int* in_sizes, int n_in,
                              void* d_out, int out_size, void* d_ws, size_t ws_size,
                              hipStream_t stream) {
    const float* qf    = (const float*)d_in[0];
    const float* pf    = (const float*)d_in[1];
    const int*   bids  = (const int*)  d_in[2];
    const float* gamma = (const float*)d_in[3];
    const float* beta  = (const float*)d_in[4];
    const float* W1    = (const float*)d_in[5];
    const float* b1    = (const float*)d_in[6];
    const float* W2    = (const float*)d_in[7];
    const float* b2    = (const float*)d_in[8];
    const float* Wc    = (const float*)d_in[9];
    const float* bc    = (const float*)d_in[10];

    float* out_class = (float*)d_out;                    // [4,100,20]
    float* out_masks = out_class + B_ * Q_ * C_;         // [N,100]

    unsigned short* me_hi = (unsigned short*)d_ws;       // [4,112,128] bf16 bits
    unsigned short* me_lo = me_hi + B_ * QPAD * D_;

    head_kernel<<<dim3(QPAD, B_), 128, 0, stream>>>(
        qf, gamma, beta, W1, b1, W2, b2, Wc, bc, out_class, me_hi, me_lo);

    mask_kernel<<<dim3(N_ / TN), 256, 0, stream>>>(
        pf, bids, me_hi, me_lo, out_masks);
}